// Round 11
// baseline (225.290 us; speedup 1.0000x reference)
//
#include <hip/hip_runtime.h>
#include <hip/hip_bf16.h>
#include <cstdint>

// Problem: B=32, T1=T2=512, D=128, gamma=1.0
// out[b] = softDTW( 1 - cos_sim(x[b], y[b]) )
//
// ws layout (floats):
//   invnx : 32*512            =     16,384
//   invny : 32*512            =     16,384
//   skew  : 32*1023*512       = 16,760,832   (cost/ln2 in anti-diagonal layout)

#define BT      32
#define TLEN    512
#define DF      128
#define NDIAG   1023          // kd = 0..1022  (kd = i-1 + j-1)
#define BIGV    1e30f
#define INV_LN2 1.44269504088896340f
#define LN2     0.69314718055994531f

// ------------------------------------------------------------- inverse norms
__global__ __launch_bounds__(256) void sdtw_invnorm(const float* __restrict__ x,
                                                    const float* __restrict__ y,
                                                    float* __restrict__ ox,
                                                    float* __restrict__ oy) {
    const float* in  = blockIdx.y ? y : x;
    float*       out = blockIdx.y ? oy : ox;
    int row = blockIdx.x * 4 + (threadIdx.x >> 6);
    int t   = threadIdx.x & 63;
    const float2* ip = reinterpret_cast<const float2*>(in + (size_t)row * DF);
    float2 v = ip[t];
    float s = v.x * v.x + v.y * v.y;
    #pragma unroll
    for (int o = 32; o; o >>= 1) s += __shfl_xor(s, o);
    if (t == 0) out[row] = 1.0f / fmaxf(sqrtf(s), 1e-12f);
}

// ------------------------------------------------- cosine-dist GEMM -> skew
// R10: register double-buffered staging — prefetch chunk kb+KC into regs
// while computing chunk kb; the vmcnt wait lands at the next LDS write,
// fully hiding global latency under ~15k cycles of FMA.
#define KC   32
#define SPAD 132

__global__ __launch_bounds__(256) void sdtw_gemm_skew(const float* __restrict__ x,
                                                      const float* __restrict__ y,
                                                      const float* __restrict__ invnx,
                                                      const float* __restrict__ invny,
                                                      float* __restrict__ skew) {
    __shared__ float smem[16640];
    float* xs = smem;                        // [KC][SPAD] transposed: xs[k][row]
    float* ys = smem + KC * SPAD;

    const int b  = blockIdx.z;
    const int r0 = blockIdx.y * 128;
    const int c0 = blockIdx.x * 128;
    const int tid = threadIdx.x;
    const int tx = tid & 15, ty = tid >> 4;

    const float* xb = x + ((size_t)b * TLEN + r0) * DF;
    const float* yb = y + ((size_t)b * TLEN + c0) * DF;

    float acc[8][8];
    #pragma unroll
    for (int i = 0; i < 8; ++i)
        #pragma unroll
        for (int j = 0; j < 8; ++j) acc[i][j] = 0.0f;

    // prefetch chunk 0 into registers (per-thread coords fixed across chunks)
    float4 rx[4], ry[4];
    #pragma unroll
    for (int i = 0; i < 4; ++i) {
        int g = tid + i * 256, row = g >> 3, kq = g & 7;
        rx[i] = *reinterpret_cast<const float4*>(xb + (size_t)row * DF + kq * 4);
        ry[i] = *reinterpret_cast<const float4*>(yb + (size_t)row * DF + kq * 4);
    }

    for (int kb = 0; kb < DF; kb += KC) {
        __syncthreads();                     // previous chunk's compute done
        #pragma unroll
        for (int i = 0; i < 4; ++i) {
            int g = tid + i * 256, row = g >> 3, kq = g & 7;
            xs[(kq * 4 + 0) * SPAD + row] = rx[i].x;
            xs[(kq * 4 + 1) * SPAD + row] = rx[i].y;
            xs[(kq * 4 + 2) * SPAD + row] = rx[i].z;
            xs[(kq * 4 + 3) * SPAD + row] = rx[i].w;
            ys[(kq * 4 + 0) * SPAD + row] = ry[i].x;
            ys[(kq * 4 + 1) * SPAD + row] = ry[i].y;
            ys[(kq * 4 + 2) * SPAD + row] = ry[i].z;
            ys[(kq * 4 + 3) * SPAD + row] = ry[i].w;
        }
        __syncthreads();
        if (kb + KC < DF) {                  // issue next chunk's loads now
            #pragma unroll
            for (int i = 0; i < 4; ++i) {
                int g = tid + i * 256, row = g >> 3, kq = g & 7;
                rx[i] = *reinterpret_cast<const float4*>(xb + (size_t)row * DF + (kb + KC) + kq * 4);
                ry[i] = *reinterpret_cast<const float4*>(yb + (size_t)row * DF + (kb + KC) + kq * 4);
            }
        }
        #pragma unroll
        for (int k = 0; k < KC; ++k) {
            float ax[8], ay[8];
            *reinterpret_cast<float4*>(&ax[0]) = *reinterpret_cast<const float4*>(&xs[k * SPAD + ty * 8]);
            *reinterpret_cast<float4*>(&ax[4]) = *reinterpret_cast<const float4*>(&xs[k * SPAD + ty * 8 + 4]);
            *reinterpret_cast<float4*>(&ay[0]) = *reinterpret_cast<const float4*>(&ys[k * SPAD + tx * 8]);
            *reinterpret_cast<float4*>(&ay[4]) = *reinterpret_cast<const float4*>(&ys[k * SPAD + tx * 8 + 4]);
            #pragma unroll
            for (int i = 0; i < 8; ++i)
                #pragma unroll
                for (int j = 0; j < 8; ++j)
                    acc[i][j] = fmaf(ax[i], ay[j], acc[i][j]);
        }
    }

    // epilogue: (1 - dot*invnx*invny)/ln2 into LDS tile [128][130]
    float rn[8], cn[8];
    #pragma unroll
    for (int i = 0; i < 8; ++i) rn[i] = invnx[b * TLEN + r0 + ty * 8 + i];
    #pragma unroll
    for (int j = 0; j < 8; ++j) cn[j] = invny[b * TLEN + c0 + tx * 8 + j];

    __syncthreads();
    float* cs = smem;
    #pragma unroll
    for (int i = 0; i < 8; ++i)
        #pragma unroll
        for (int j = 0; j < 8; ++j)
            cs[(ty * 8 + i) * 130 + tx * 8 + j] =
                (1.0f - acc[i][j] * rn[i] * cn[j]) * INV_LN2;
    __syncthreads();

    float* sk = skew + (size_t)b * (NDIAG * TLEN);
    const int wv = tid >> 6, l = tid & 63;
    for (int dd = wv; dd < 255; dd += 4) {
        int lo = max(0, dd - 127), hi = min(127, dd);
        size_t base = (size_t)(r0 + c0 + dd) * TLEN + r0;
        for (int rb = lo; rb <= hi; rb += 64) {
            int rl = rb + l;
            if (rl <= hi) sk[base + rl] = cs[rl * 129 + dd];   // rl*130 + (dd-rl)
        }
    }
}

// ----------------------------------------------------------------- DTW DP
// R10: TWO batches per block (16 waves, 1024 threads). Waves 0-7 -> batch
// 2*blockIdx.x, waves 8-15 -> +1. Both batches share the 16-phase segment
// barrier cadence; every SIMD hosts waves from BOTH batches with overlapping
// active windows -> guaranteed >=2 co-active waves/SIMD (independent of the
// hardware wave->SIMD mapping), filling softmin-chain stalls.
// Per batch: 8 waves, lane owns row r = 64*chunk + lt; chunk c processes
// diag kd at phase p = kd + 16c; chunk remap c = ((ww&3)<<1)|(ww>>2) kept
// (neutral). Segment modes: JUNK / PARTIAL(mask+clamp; sw==-1 warm-up
// re-primes prefetch) / INTERIOR. Lane-0 patch via DPP wave_shr:1 with
// old=bd_up; dg carried in dgs. Boundary float4 quads through
// bnd4[bg][chunk+1] (write) / bnd4[bg][chunk] (hoisted read, written a full
// segment earlier -> race-free). 71 segments * 16 = 1136 phases; answer:
// diag 1022 (even -> Q) of chunk 7 lane 63 = local tid 511 of each half.

__device__ __forceinline__ int clampi(int v) {
    return v < 0 ? 0 : (v > NDIAG - 1 ? NDIAG - 1 : v);
}

__device__ __forceinline__ float dpp_shr1_old(float old, float x) {
    return __builtin_bit_cast(float,
        __builtin_amdgcn_update_dpp(__builtin_bit_cast(int, old),
                                    __builtin_bit_cast(int, x),
                                    0x138 /*wave_shr:1*/, 0xF, 0xF, false));
}

#define PH(s, CC, PN, PO, NQC, MASKED, CLAMPED)                                \
  {                                                                            \
    float up_ = dpp_shr1_old(bd_up, PN);     /* lane0 <- bd_up */              \
    float dg_ = dgs;                         /* patched up_ of prev phase */   \
    float m_   = fminf(fminf(dg_, PN), up_);                                   \
    float mid_ = __builtin_amdgcn_fmed3f(dg_, PN, up_);                        \
    float mx_  = fmaxf(fmaxf(dg_, PN), up_);                                   \
    float e_   = 1.0f + __builtin_amdgcn_exp2f(m_ - mid_)                      \
                      + __builtin_amdgcn_exp2f(m_ - mx_);                      \
    float v_   = CC + m_ - __builtin_amdgcn_logf(e_);                          \
    PO = (MASKED) ? (((unsigned)(vb0 + (s)) < 512u) ? v_ : vBig) : v_;         \
    if (((s) & 3) == 0) bq.x = PO;                                             \
    if (((s) & 3) == 1) bq.y = PO;                                             \
    if (((s) & 3) == 2) bq.z = PO;                                             \
    if (((s) & 3) == 3) { bq.w = PO;                                           \
      if (lt == 63) bnd4[bg][c + 1][(q0 + ((s) >> 2)) & 7] = bq; }             \
    bd_up = (NQC);                                                             \
    dgs = up_;                                                                 \
    { int kl_ = kd0 + (s) + 8; if (CLAMPED) kl_ = clampi(kl_);                 \
      CC = skb[(size_t)kl_ * TLEN]; }                                          \
  }

#define SEG_BODY(MASKED, CLAMPED)                                              \
    PH(0,  c0, P, Q, nq0.x, MASKED, CLAMPED) PH(1,  c1, Q, P, nq0.y, MASKED, CLAMPED) \
    PH(2,  c2, P, Q, nq0.z, MASKED, CLAMPED) PH(3,  c3, Q, P, nq0.w, MASKED, CLAMPED) \
    PH(4,  c4, P, Q, nq1.x, MASKED, CLAMPED) PH(5,  c5, Q, P, nq1.y, MASKED, CLAMPED) \
    PH(6,  c6, P, Q, nq1.z, MASKED, CLAMPED) PH(7,  c7, Q, P, nq1.w, MASKED, CLAMPED) \
    PH(8,  c0, P, Q, nq2.x, MASKED, CLAMPED) PH(9,  c1, Q, P, nq2.y, MASKED, CLAMPED) \
    PH(10, c2, P, Q, nq2.z, MASKED, CLAMPED) PH(11, c3, Q, P, nq2.w, MASKED, CLAMPED) \
    PH(12, c4, P, Q, nq3.x, MASKED, CLAMPED) PH(13, c5, Q, P, nq3.y, MASKED, CLAMPED) \
    PH(14, c6, P, Q, nq3.z, MASKED, CLAMPED) PH(15, c7, Q, P, nq3.w, MASKED, CLAMPED)

#define PRIME(K)                                                               \
    c0 = skb[(size_t)clampi((K) + 0) * TLEN];                                  \
    c1 = skb[(size_t)clampi((K) + 1) * TLEN];                                  \
    c2 = skb[(size_t)clampi((K) + 2) * TLEN];                                  \
    c3 = skb[(size_t)clampi((K) + 3) * TLEN];                                  \
    c4 = skb[(size_t)clampi((K) + 4) * TLEN];                                  \
    c5 = skb[(size_t)clampi((K) + 5) * TLEN];                                  \
    c6 = skb[(size_t)clampi((K) + 6) * TLEN];                                  \
    c7 = skb[(size_t)clampi((K) + 7) * TLEN];

__global__ __launch_bounds__(1024) void sdtw_dp(const float* __restrict__ skew,
                                                float* __restrict__ out) {
    const int tid = threadIdx.x;
    const int bg  = tid >> 9;                    // batch half (0/1)
    const int b   = blockIdx.x * 2 + bg;
    const int t5  = tid & 511;                   // local tid within batch
    const int ww  = t5 >> 6;                     // wave id within batch
    const int c   = ((ww & 3) << 1) | (ww >> 2); // chunk (remap, neutral)
    const int lt  = tid & 63;
    const int row = 64 * c + lt;
    const float* skb = skew + (size_t)b * (NDIAG * TLEN) + row;

    __shared__ float4 bnd4[2][9][8];             // [batch half][consumer chunk][slot]
    if (tid < 576) ((float*)bnd4)[tid] = BIGV;

    float P = BIGV, Q = BIGV;
    float vBig  = BIGV;
    float bd_up = BIGV;
    // dgs: patched up_ of prev phase. chunk0 lane0 (t5==0) sees R(0,0)=0 at kd=0.
    float dgs   = (t5 == 0) ? 0.0f : BIGV;
    float4 bq = make_float4(BIGV, BIGV, BIGV, BIGV);

    __syncthreads();

    float c0, c1, c2, c3, c4, c5, c6, c7;
    PRIME(-16 * c)                               // real for chunk 0; re-primed at warm-up

    for (int s = 0; s < 71; ++s) {
        const int sw  = s - 5 * c;               // wave-uniform
        const int kd0 = 16 * (s - c);
        const int q0  = (kd0 >> 2) & 7;
        const int vb0 = kd0 - row;

        if (sw >= -1 && sw <= 35) {
            // hoisted boundary quads (all written in segment s-1 -> race-free)
            float4 nq0 = bnd4[bg][c][q0];
            float4 nq1 = bnd4[bg][c][(q0 + 1) & 7];
            float4 nq2 = bnd4[bg][c][(q0 + 2) & 7];
            float4 nq3 = bnd4[bg][c][(q0 + 3) & 7];
            if (sw == -1) { PRIME(kd0) }         // warm-up: re-prime prefetch
            if (sw >= 4 && sw <= 31) { SEG_BODY(0, 0) }   // interior
            else                     { SEG_BODY(1, 1) }   // staircase/warm-up
        } else {
            if (lt == 63) {                      // junk: keep boundary cadence
                float4 bigq = make_float4(BIGV, BIGV, BIGV, BIGV);
                bnd4[bg][c + 1][q0]           = bigq;
                bnd4[bg][c + 1][(q0 + 1) & 7] = bigq;
                bnd4[bg][c + 1][(q0 + 2) & 7] = bigq;
                bnd4[bg][c + 1][(q0 + 3) & 7] = bigq;
            }
        }
        __syncthreads();
    }

    if (t5 == 511) out[b] = Q * LN2;             // chunk 7, row 511: R'(512,512)*ln2
}

// ---------------------------------------------------------------- launcher
extern "C" void kernel_launch(void* const* d_in, const int* in_sizes, int n_in,
                              void* d_out, int out_size, void* d_ws, size_t ws_size,
                              hipStream_t stream) {
    const float* x = (const float*)d_in[0];
    const float* y = (const float*)d_in[1];
    float* outp = (float*)d_out;

    float* invnx = (float*)d_ws;                          //  16,384 floats
    float* invny = invnx + (size_t)BT * TLEN;             //  16,384 floats
    float* skew  = invny + (size_t)BT * TLEN;             //  16,760,832 floats

    sdtw_invnorm<<<dim3(BT * TLEN / 4, 2), dim3(256), 0, stream>>>(x, y, invnx, invny);
    sdtw_gemm_skew<<<dim3(4, 4, BT), dim3(256), 0, stream>>>(x, y, invnx, invny, skew);
    sdtw_dp<<<dim3(BT / 2), dim3(1024), 0, stream>>>(skew, outp);
}

// Round 13
// 187.966 us; speedup vs baseline: 1.1986x; 1.1986x over previous
//
#include <hip/hip_runtime.h>
#include <hip/hip_bf16.h>
#include <cstdint>

// Problem: B=32, T1=T2=512, D=128, gamma=1.0
// out[b] = softDTW( 1 - cos_sim(x[b], y[b]) )
//
// ws layout (floats):
//   skew : 32*1023*512 = 16,760,832   (cost/ln2 in anti-diagonal layout)

#define BT      32
#define TLEN    512
#define DF      128
#define NDIAG   1023          // kd = 0..1022  (kd = i-1 + j-1)
#define BIGV    1e30f
#define INV_LN2 1.44269504088896340f
#define LN2     0.69314718055994531f

// ------------------------------------------------- cosine-dist GEMM -> skew
// Norms fused: per-thread sumsq partials during staging, 3-level shfl_xor
// reduce per aligned 8-lane group, LDS broadcast. Register double-buffered
// global->LDS staging.
#define KC   32
#define SPAD 132

__global__ __launch_bounds__(256) void sdtw_gemm_skew(const float* __restrict__ x,
                                                      const float* __restrict__ y,
                                                      float* __restrict__ skew) {
    __shared__ float smem[16640];
    __shared__ float rsx[128], rsy[128];     // row/col sumsq
    float* xs = smem;                        // [KC][SPAD] transposed: xs[k][row]
    float* ys = smem + KC * SPAD;

    const int b  = blockIdx.z;
    const int r0 = blockIdx.y * 128;
    const int c0 = blockIdx.x * 128;
    const int tid = threadIdx.x;
    const int tx = tid & 15, ty = tid >> 4;

    const float* xb = x + ((size_t)b * TLEN + r0) * DF;
    const float* yb = y + ((size_t)b * TLEN + c0) * DF;

    float acc[8][8];
    #pragma unroll
    for (int i = 0; i < 8; ++i)
        #pragma unroll
        for (int j = 0; j < 8; ++j) acc[i][j] = 0.0f;

    float psx[4] = {0, 0, 0, 0}, psy[4] = {0, 0, 0, 0};

    float4 rx[4], ry[4];
    #pragma unroll
    for (int i = 0; i < 4; ++i) {
        int g = tid + i * 256, row = g >> 3, kq = g & 7;
        rx[i] = *reinterpret_cast<const float4*>(xb + (size_t)row * DF + kq * 4);
        ry[i] = *reinterpret_cast<const float4*>(yb + (size_t)row * DF + kq * 4);
    }

    for (int kb = 0; kb < DF; kb += KC) {
        __syncthreads();
        #pragma unroll
        for (int i = 0; i < 4; ++i) {
            int g = tid + i * 256, row = g >> 3, kq = g & 7;
            xs[(kq * 4 + 0) * SPAD + row] = rx[i].x;
            xs[(kq * 4 + 1) * SPAD + row] = rx[i].y;
            xs[(kq * 4 + 2) * SPAD + row] = rx[i].z;
            xs[(kq * 4 + 3) * SPAD + row] = rx[i].w;
            ys[(kq * 4 + 0) * SPAD + row] = ry[i].x;
            ys[(kq * 4 + 1) * SPAD + row] = ry[i].y;
            ys[(kq * 4 + 2) * SPAD + row] = ry[i].z;
            ys[(kq * 4 + 3) * SPAD + row] = ry[i].w;
            psx[i] = fmaf(rx[i].x, rx[i].x, psx[i]);
            psx[i] = fmaf(rx[i].y, rx[i].y, psx[i]);
            psx[i] = fmaf(rx[i].z, rx[i].z, psx[i]);
            psx[i] = fmaf(rx[i].w, rx[i].w, psx[i]);
            psy[i] = fmaf(ry[i].x, ry[i].x, psy[i]);
            psy[i] = fmaf(ry[i].y, ry[i].y, psy[i]);
            psy[i] = fmaf(ry[i].z, ry[i].z, psy[i]);
            psy[i] = fmaf(ry[i].w, ry[i].w, psy[i]);
        }
        __syncthreads();
        if (kb + KC < DF) {
            #pragma unroll
            for (int i = 0; i < 4; ++i) {
                int g = tid + i * 256, row = g >> 3, kq = g & 7;
                rx[i] = *reinterpret_cast<const float4*>(xb + (size_t)row * DF + (kb + KC) + kq * 4);
                ry[i] = *reinterpret_cast<const float4*>(yb + (size_t)row * DF + (kb + KC) + kq * 4);
            }
        }
        #pragma unroll
        for (int k = 0; k < KC; ++k) {
            float ax[8], ay[8];
            *reinterpret_cast<float4*>(&ax[0]) = *reinterpret_cast<const float4*>(&xs[k * SPAD + ty * 8]);
            *reinterpret_cast<float4*>(&ax[4]) = *reinterpret_cast<const float4*>(&xs[k * SPAD + ty * 8 + 4]);
            *reinterpret_cast<float4*>(&ay[0]) = *reinterpret_cast<const float4*>(&ys[k * SPAD + tx * 8]);
            *reinterpret_cast<float4*>(&ay[4]) = *reinterpret_cast<const float4*>(&ys[k * SPAD + tx * 8 + 4]);
            #pragma unroll
            for (int i = 0; i < 8; ++i)
                #pragma unroll
                for (int j = 0; j < 8; ++j)
                    acc[i][j] = fmaf(ax[i], ay[j], acc[i][j]);
        }
    }

    #pragma unroll
    for (int i = 0; i < 4; ++i) {
        #pragma unroll
        for (int o = 1; o <= 4; o <<= 1) {
            psx[i] += __shfl_xor(psx[i], o);
            psy[i] += __shfl_xor(psy[i], o);
        }
    }
    if ((tid & 7) == 0) {
        #pragma unroll
        for (int i = 0; i < 4; ++i) {
            rsx[(tid + i * 256) >> 3] = psx[i];
            rsy[(tid + i * 256) >> 3] = psy[i];
        }
    }

    __syncthreads();
    float rn[8], cn[8];
    #pragma unroll
    for (int i = 0; i < 8; ++i) rn[i] = 1.0f / fmaxf(sqrtf(rsx[ty * 8 + i]), 1e-12f);
    #pragma unroll
    for (int j = 0; j < 8; ++j) cn[j] = 1.0f / fmaxf(sqrtf(rsy[tx * 8 + j]), 1e-12f);

    float* cs = smem;
    #pragma unroll
    for (int i = 0; i < 8; ++i)
        #pragma unroll
        for (int j = 0; j < 8; ++j)
            cs[(ty * 8 + i) * 130 + tx * 8 + j] =
                (1.0f - acc[i][j] * rn[i] * cn[j]) * INV_LN2;
    __syncthreads();

    float* sk = skew + (size_t)b * (NDIAG * TLEN);
    const int wv = tid >> 6, l = tid & 63;
    for (int dd = wv; dd < 255; dd += 4) {
        int lo = max(0, dd - 127), hi = min(127, dd);
        size_t base = (size_t)(r0 + c0 + dd) * TLEN + r0;
        for (int rb = lo; rb <= hi; rb += 64) {
            int rl = rb + l;
            if (rl <= hi) sk[base + rl] = cs[rl * 129 + dd];   // rl*130 + (dd-rl)
        }
    }
}

// ----------------------------------------------------------------- DTW DP
// Barrier-free producer/consumer pipeline, R11 bugs fixed.
// 8 waves (512 thr), chunk c = wave, lane owns row 64c+lt; chunk c handles
// diag kd at phase kd+16c; segments of 16 phases. Per-chunk LDS progress
// counters + 16-quad boundary rings.
// Gates: consumer (active segs only) spins prog[c-1] >= s-1; producer spins
// prog[c+1] >= s-3 (ring reuse distance 4 segs). Compiler fence after gates.
// FIXES vs R11: (1) chunks c<7 run 4 EPILOGUE segments (sw 36..39) writing
// BIGV quads in normal cadence + publishing -> send(c)=5c+39 exactly covers
// consumer c+1's last gate prog[c] >= 5(c+1)+34 = 5c+39; chunk 7's gate at
// s=70 needs prog[6] >= 69 = send(6). (2) those BIGV quads replace the
// barrier version's junk writes -> no stale ring data for diags past the
// producer's active range. Deadlock-free: seg s waits only on neighbor segs
// <= s-1 -> DAG. Answer: diag 1022 (Q) of chunk 7 lane 63 (tid 511).

__device__ __forceinline__ int clampi(int v) {
    return v < 0 ? 0 : (v > NDIAG - 1 ? NDIAG - 1 : v);
}

__device__ __forceinline__ float dpp_shr1_old(float old, float x) {
    return __builtin_bit_cast(float,
        __builtin_amdgcn_update_dpp(__builtin_bit_cast(int, old),
                                    __builtin_bit_cast(int, x),
                                    0x138 /*wave_shr:1*/, 0xF, 0xF, false));
}

#define PH(s, CC, PN, PO, NQC, MASKED, CLAMPED)                                \
  {                                                                            \
    float up_ = dpp_shr1_old(bd_up, PN);     /* lane0 <- bd_up */              \
    float dg_ = dgs;                         /* patched up_ of prev phase */   \
    float m_   = fminf(fminf(dg_, PN), up_);                                   \
    float mid_ = __builtin_amdgcn_fmed3f(dg_, PN, up_);                        \
    float mx_  = fmaxf(fmaxf(dg_, PN), up_);                                   \
    float e_   = 1.0f + __builtin_amdgcn_exp2f(m_ - mid_)                      \
                      + __builtin_amdgcn_exp2f(m_ - mx_);                      \
    float v_   = CC + m_ - __builtin_amdgcn_logf(e_);                          \
    PO = (MASKED) ? (((unsigned)(vb0 + (s)) < 512u) ? v_ : vBig) : v_;         \
    if (((s) & 3) == 0) bq.x = PO;                                             \
    if (((s) & 3) == 1) bq.y = PO;                                             \
    if (((s) & 3) == 2) bq.z = PO;                                             \
    if (((s) & 3) == 3) { bq.w = PO;                                           \
      if (lt == 63) bnd4[c + 1][(q0 + ((s) >> 2)) & 15] = bq; }                \
    bd_up = (NQC);                                                             \
    dgs = up_;                                                                 \
    { int kl_ = kd0 + (s) + 8; if (CLAMPED) kl_ = clampi(kl_);                 \
      CC = skb[(size_t)kl_ * TLEN]; }                                          \
  }

#define SEG_BODY(MASKED, CLAMPED)                                              \
    PH(0,  c0, P, Q, nq0.x, MASKED, CLAMPED) PH(1,  c1, Q, P, nq0.y, MASKED, CLAMPED) \
    PH(2,  c2, P, Q, nq0.z, MASKED, CLAMPED) PH(3,  c3, Q, P, nq0.w, MASKED, CLAMPED) \
    PH(4,  c4, P, Q, nq1.x, MASKED, CLAMPED) PH(5,  c5, Q, P, nq1.y, MASKED, CLAMPED) \
    PH(6,  c6, P, Q, nq1.z, MASKED, CLAMPED) PH(7,  c7, Q, P, nq1.w, MASKED, CLAMPED) \
    PH(8,  c0, P, Q, nq2.x, MASKED, CLAMPED) PH(9,  c1, Q, P, nq2.y, MASKED, CLAMPED) \
    PH(10, c2, P, Q, nq2.z, MASKED, CLAMPED) PH(11, c3, Q, P, nq2.w, MASKED, CLAMPED) \
    PH(12, c4, P, Q, nq3.x, MASKED, CLAMPED) PH(13, c5, Q, P, nq3.y, MASKED, CLAMPED) \
    PH(14, c6, P, Q, nq3.z, MASKED, CLAMPED) PH(15, c7, Q, P, nq3.w, MASKED, CLAMPED)

#define PRIME(K)                                                               \
    c0 = skb[(size_t)clampi((K) + 0) * TLEN];                                  \
    c1 = skb[(size_t)clampi((K) + 1) * TLEN];                                  \
    c2 = skb[(size_t)clampi((K) + 2) * TLEN];                                  \
    c3 = skb[(size_t)clampi((K) + 3) * TLEN];                                  \
    c4 = skb[(size_t)clampi((K) + 4) * TLEN];                                  \
    c5 = skb[(size_t)clampi((K) + 5) * TLEN];                                  \
    c6 = skb[(size_t)clampi((K) + 6) * TLEN];                                  \
    c7 = skb[(size_t)clampi((K) + 7) * TLEN];

__global__ __launch_bounds__(512) void sdtw_dp(const float* __restrict__ skew,
                                               float* __restrict__ out) {
    const int b   = blockIdx.x;
    const int tid = threadIdx.x;
    const int c   = tid >> 6;                    // chunk = wave id
    const int lt  = tid & 63;
    const int row = 64 * c + lt;
    const float* skb = skew + (size_t)b * (NDIAG * TLEN) + row;

    __shared__ float4 bnd4[9][16];               // [consumer chunk][ring slot]
    __shared__ int    prog[8];                   // last completed segment
    {
        float* bp = (float*)bnd4;
        bp[tid] = BIGV;
        if (tid < 64) bp[512 + tid] = BIGV;
        if (tid < 8)  prog[tid] = 5 * tid - 2;
    }

    float P = BIGV, Q = BIGV;
    float vBig  = BIGV;
    float bd_up = BIGV;
    float dgs   = (tid == 0) ? 0.0f : BIGV;      // R(0,0)=0 at kd=0, chunk0 lane0
    float4 bq = make_float4(BIGV, BIGV, BIGV, BIGV);

    __syncthreads();                             // LDS init visible; only barrier

    float c0, c1, c2, c3, c4, c5, c6, c7;
    PRIME(-16 * c)                               // real for chunk 0; re-primed at warm-up

    const int sbeg = (c == 0) ? 0 : 5 * c - 1;
    const int send = (c < 7) ? 5 * c + 39 : 70;  // c<7: +4 epilogue segments

    for (int s = sbeg; s <= send; ++s) {
        const int sw  = s - 5 * c;               // in [-1, 39]
        const int kd0 = 16 * (s - c);
        const int q0  = (kd0 >> 2) & 15;
        const int vb0 = kd0 - row;

        if (sw <= 35) {                          // -------- active segment
            if (c > 0) { while (*(volatile int*)&prog[c - 1] < s - 1) __builtin_amdgcn_s_sleep(1); }
            if (c < 7) { while (*(volatile int*)&prog[c + 1] < s - 3) __builtin_amdgcn_s_sleep(1); }
            asm volatile("" ::: "memory");       // no hoisting reads above gates

            float4 nq0 = bnd4[c][q0];
            float4 nq1 = bnd4[c][(q0 + 1) & 15];
            float4 nq2 = bnd4[c][(q0 + 2) & 15];
            float4 nq3 = bnd4[c][(q0 + 3) & 15];

            if (sw == -1) { PRIME(kd0) }         // warm-up: re-prime prefetch
            if (sw >= 4 && sw <= 31) { SEG_BODY(0, 0) }   // interior
            else                     { SEG_BODY(1, 1) }   // staircase/warm-up
        } else {                                 // -------- epilogue (c<7 only)
            if (c < 7) { while (*(volatile int*)&prog[c + 1] < s - 3) __builtin_amdgcn_s_sleep(1); }
            asm volatile("" ::: "memory");
            if (lt == 63) {                      // BIGV quads, normal cadence
                float4 bigq = make_float4(BIGV, BIGV, BIGV, BIGV);
                bnd4[c + 1][q0]            = bigq;
                bnd4[c + 1][(q0 + 1) & 15] = bigq;
                bnd4[c + 1][(q0 + 2) & 15] = bigq;
                bnd4[c + 1][(q0 + 3) & 15] = bigq;
            }
        }

        if (lt == 63) {                          // publish: segment s complete
            asm volatile("s_waitcnt lgkmcnt(0)" ::: "memory");
            *(volatile int*)&prog[c] = s;
        }
    }

    if (tid == 511) out[b] = Q * LN2;            // chunk 7, row 511: R'(512,512)*ln2
}

// ---------------------------------------------------------------- launcher
extern "C" void kernel_launch(void* const* d_in, const int* in_sizes, int n_in,
                              void* d_out, int out_size, void* d_ws, size_t ws_size,
                              hipStream_t stream) {
    const float* x = (const float*)d_in[0];
    const float* y = (const float*)d_in[1];
    float* outp = (float*)d_out;

    float* skew = (float*)d_ws;                  // 16,760,832 floats

    sdtw_gemm_skew<<<dim3(4, 4, BT), dim3(256), 0, stream>>>(x, y, skew);
    sdtw_dp<<<dim3(BT), dim3(512), 0, stream>>>(skew, outp);
}

// Round 14
// 154.723 us; speedup vs baseline: 1.4561x; 1.2149x over previous
//
#include <hip/hip_runtime.h>
#include <hip/hip_bf16.h>
#include <cstdint>

// Problem: B=32, T1=T2=512, D=128, gamma=1.0
// out[b] = softDTW( 1 - cos_sim(x[b], y[b]) )
//
// ws layout (floats):
//   skew : 32*1023*512 = 16,760,832   (cost/ln2 in anti-diagonal layout)

#define BT      32
#define TLEN    512
#define DF      128
#define NDIAG   1023          // kd = 0..1022  (kd = i-1 + j-1)
#define BIGV    1e30f
#define INV_LN2 1.44269504088896340f
#define LN2     0.69314718055994531f

// ------------------------------------------------- cosine-dist GEMM -> skew
// Norms fused (sumsq during staging + 8-lane shfl_xor reduce + LDS bcast).
// R14: epilogue processes the 128x128 tile in TWO 64-row halves through a
// cs[64][130] LDS buffer that fits inside the K-loop's 33.8 KB footprint ->
// LDS/block 67 KB -> 35 KB -> 4 blocks/CU (was 2), doubling co-resident
// FMA issue to hide ds_read latency.
#define KC   32
#define SPAD 132

__global__ __launch_bounds__(256) void sdtw_gemm_skew(const float* __restrict__ x,
                                                      const float* __restrict__ y,
                                                      float* __restrict__ skew) {
    __shared__ float smem[8448];             // K: xs[32][132]+ys[32][132]; epi: cs[64][130]
    __shared__ float rsx[128], rsy[128];     // row/col sumsq
    float* xs = smem;                        // [KC][SPAD] transposed: xs[k][row]
    float* ys = smem + KC * SPAD;

    const int b  = blockIdx.z;
    const int r0 = blockIdx.y * 128;
    const int c0 = blockIdx.x * 128;
    const int tid = threadIdx.x;
    const int tx = tid & 15, ty = tid >> 4;

    const float* xb = x + ((size_t)b * TLEN + r0) * DF;
    const float* yb = y + ((size_t)b * TLEN + c0) * DF;

    float acc[8][8];
    #pragma unroll
    for (int i = 0; i < 8; ++i)
        #pragma unroll
        for (int j = 0; j < 8; ++j) acc[i][j] = 0.0f;

    float psx[4] = {0, 0, 0, 0}, psy[4] = {0, 0, 0, 0};

    float4 rx[4], ry[4];
    #pragma unroll
    for (int i = 0; i < 4; ++i) {
        int g = tid + i * 256, row = g >> 3, kq = g & 7;
        rx[i] = *reinterpret_cast<const float4*>(xb + (size_t)row * DF + kq * 4);
        ry[i] = *reinterpret_cast<const float4*>(yb + (size_t)row * DF + kq * 4);
    }

    for (int kb = 0; kb < DF; kb += KC) {
        __syncthreads();
        #pragma unroll
        for (int i = 0; i < 4; ++i) {
            int g = tid + i * 256, row = g >> 3, kq = g & 7;
            xs[(kq * 4 + 0) * SPAD + row] = rx[i].x;
            xs[(kq * 4 + 1) * SPAD + row] = rx[i].y;
            xs[(kq * 4 + 2) * SPAD + row] = rx[i].z;
            xs[(kq * 4 + 3) * SPAD + row] = rx[i].w;
            ys[(kq * 4 + 0) * SPAD + row] = ry[i].x;
            ys[(kq * 4 + 1) * SPAD + row] = ry[i].y;
            ys[(kq * 4 + 2) * SPAD + row] = ry[i].z;
            ys[(kq * 4 + 3) * SPAD + row] = ry[i].w;
            psx[i] = fmaf(rx[i].x, rx[i].x, psx[i]);
            psx[i] = fmaf(rx[i].y, rx[i].y, psx[i]);
            psx[i] = fmaf(rx[i].z, rx[i].z, psx[i]);
            psx[i] = fmaf(rx[i].w, rx[i].w, psx[i]);
            psy[i] = fmaf(ry[i].x, ry[i].x, psy[i]);
            psy[i] = fmaf(ry[i].y, ry[i].y, psy[i]);
            psy[i] = fmaf(ry[i].z, ry[i].z, psy[i]);
            psy[i] = fmaf(ry[i].w, ry[i].w, psy[i]);
        }
        __syncthreads();
        if (kb + KC < DF) {
            #pragma unroll
            for (int i = 0; i < 4; ++i) {
                int g = tid + i * 256, row = g >> 3, kq = g & 7;
                rx[i] = *reinterpret_cast<const float4*>(xb + (size_t)row * DF + (kb + KC) + kq * 4);
                ry[i] = *reinterpret_cast<const float4*>(yb + (size_t)row * DF + (kb + KC) + kq * 4);
            }
        }
        #pragma unroll
        for (int k = 0; k < KC; ++k) {
            float ax[8], ay[8];
            *reinterpret_cast<float4*>(&ax[0]) = *reinterpret_cast<const float4*>(&xs[k * SPAD + ty * 8]);
            *reinterpret_cast<float4*>(&ax[4]) = *reinterpret_cast<const float4*>(&xs[k * SPAD + ty * 8 + 4]);
            *reinterpret_cast<float4*>(&ay[0]) = *reinterpret_cast<const float4*>(&ys[k * SPAD + tx * 8]);
            *reinterpret_cast<float4*>(&ay[4]) = *reinterpret_cast<const float4*>(&ys[k * SPAD + tx * 8 + 4]);
            #pragma unroll
            for (int i = 0; i < 8; ++i)
                #pragma unroll
                for (int j = 0; j < 8; ++j)
                    acc[i][j] = fmaf(ax[i], ay[j], acc[i][j]);
        }
    }

    // sumsq reduce within each aligned 8-lane group
    #pragma unroll
    for (int i = 0; i < 4; ++i) {
        #pragma unroll
        for (int o = 1; o <= 4; o <<= 1) {
            psx[i] += __shfl_xor(psx[i], o);
            psy[i] += __shfl_xor(psy[i], o);
        }
    }
    if ((tid & 7) == 0) {
        #pragma unroll
        for (int i = 0; i < 4; ++i) {
            rsx[(tid + i * 256) >> 3] = psx[i];
            rsy[(tid + i * 256) >> 3] = psy[i];
        }
    }

    __syncthreads();
    float rn[8], cn[8];
    #pragma unroll
    for (int i = 0; i < 8; ++i) rn[i] = 1.0f / fmaxf(sqrtf(rsx[ty * 8 + i]), 1e-12f);
    #pragma unroll
    for (int j = 0; j < 8; ++j) cn[j] = 1.0f / fmaxf(sqrtf(rsy[tx * 8 + j]), 1e-12f);

    float* cs = smem;                        // [64][130], reuses K-loop space
    float* sk = skew + (size_t)b * (NDIAG * TLEN);
    const int wv = tid >> 6, l = tid & 63;

    #pragma unroll
    for (int h = 0; h < 2; ++h) {
        if ((ty >> 3) == h) {                // rows h*64 .. h*64+63 (ty&7 -> local/8)
            #pragma unroll
            for (int i = 0; i < 8; ++i)
                #pragma unroll
                for (int j = 0; j < 8; ++j)
                    cs[((ty & 7) * 8 + i) * 130 + tx * 8 + j] =
                        (1.0f - acc[i][j] * rn[i] * cn[j]) * INV_LN2;
        }
        __syncthreads();
        // scatter this half's rows of every anti-diagonal
        for (int dd = wv; dd < 255; dd += 4) {
            int lo = max(h * 64, dd - 127), hi = min(h * 64 + 63, dd);
            int rl = lo + l;
            if (rl <= hi)
                sk[(size_t)(r0 + c0 + dd) * TLEN + r0 + rl] =
                    cs[(rl - h * 64) * 130 + (dd - rl)];
        }
        __syncthreads();
    }
}

// ----------------------------------------------------------------- DTW DP
// (R9 kernel, best measured: ~91 us.) 8 waves per batch (512 threads), lane
// owns row r = 64*chunk + lt; chunk remap c = ((ww&3)<<1)|(ww>>2). Chunk c
// processes diag kd at phase p = kd + 16c; one __syncthreads per 16-phase
// segment. Modes: JUNK / PARTIAL(mask+clamp; sw==-1 warm-up re-primes
// prefetch) / INTERIOR. Lane-0 patch via DPP wave_shr:1 old=bd_up; dg
// carried in dgs. Boundary quads hoisted at segment start (written a full
// segment earlier -> race-free). 71 segments * 16 = 1136 phases; answer:
// diag 1022 (even -> Q) of chunk 7 lane 63 = tid 511.

__device__ __forceinline__ int clampi(int v) {
    return v < 0 ? 0 : (v > NDIAG - 1 ? NDIAG - 1 : v);
}

__device__ __forceinline__ float dpp_shr1_old(float old, float x) {
    return __builtin_bit_cast(float,
        __builtin_amdgcn_update_dpp(__builtin_bit_cast(int, old),
                                    __builtin_bit_cast(int, x),
                                    0x138 /*wave_shr:1*/, 0xF, 0xF, false));
}

#define PH(s, CC, PN, PO, NQC, MASKED, CLAMPED)                                \
  {                                                                            \
    float up_ = dpp_shr1_old(bd_up, PN);     /* lane0 <- bd_up */              \
    float dg_ = dgs;                         /* patched up_ of prev phase */   \
    float m_   = fminf(fminf(dg_, PN), up_);                                   \
    float mid_ = __builtin_amdgcn_fmed3f(dg_, PN, up_);                        \
    float mx_  = fmaxf(fmaxf(dg_, PN), up_);                                   \
    float e_   = 1.0f + __builtin_amdgcn_exp2f(m_ - mid_)                      \
                      + __builtin_amdgcn_exp2f(m_ - mx_);                      \
    float v_   = CC + m_ - __builtin_amdgcn_logf(e_);                          \
    PO = (MASKED) ? (((unsigned)(vb0 + (s)) < 512u) ? v_ : vBig) : v_;         \
    if (((s) & 3) == 0) bq.x = PO;                                             \
    if (((s) & 3) == 1) bq.y = PO;                                             \
    if (((s) & 3) == 2) bq.z = PO;                                             \
    if (((s) & 3) == 3) { bq.w = PO;                                           \
      if (lt == 63) bnd4[c + 1][(q0 + ((s) >> 2)) & 7] = bq; }                 \
    bd_up = (NQC);                                                             \
    dgs = up_;                                                                 \
    { int kl_ = kd0 + (s) + 8; if (CLAMPED) kl_ = clampi(kl_);                 \
      CC = skb[(size_t)kl_ * TLEN]; }                                          \
  }

#define SEG_BODY(MASKED, CLAMPED)                                              \
    PH(0,  c0, P, Q, nq0.x, MASKED, CLAMPED) PH(1,  c1, Q, P, nq0.y, MASKED, CLAMPED) \
    PH(2,  c2, P, Q, nq0.z, MASKED, CLAMPED) PH(3,  c3, Q, P, nq0.w, MASKED, CLAMPED) \
    PH(4,  c4, P, Q, nq1.x, MASKED, CLAMPED) PH(5,  c5, Q, P, nq1.y, MASKED, CLAMPED) \
    PH(6,  c6, P, Q, nq1.z, MASKED, CLAMPED) PH(7,  c7, Q, P, nq1.w, MASKED, CLAMPED) \
    PH(8,  c0, P, Q, nq2.x, MASKED, CLAMPED) PH(9,  c1, Q, P, nq2.y, MASKED, CLAMPED) \
    PH(10, c2, P, Q, nq2.z, MASKED, CLAMPED) PH(11, c3, Q, P, nq2.w, MASKED, CLAMPED) \
    PH(12, c4, P, Q, nq3.x, MASKED, CLAMPED) PH(13, c5, Q, P, nq3.y, MASKED, CLAMPED) \
    PH(14, c6, P, Q, nq3.z, MASKED, CLAMPED) PH(15, c7, Q, P, nq3.w, MASKED, CLAMPED)

#define PRIME(K)                                                               \
    c0 = skb[(size_t)clampi((K) + 0) * TLEN];                                  \
    c1 = skb[(size_t)clampi((K) + 1) * TLEN];                                  \
    c2 = skb[(size_t)clampi((K) + 2) * TLEN];                                  \
    c3 = skb[(size_t)clampi((K) + 3) * TLEN];                                  \
    c4 = skb[(size_t)clampi((K) + 4) * TLEN];                                  \
    c5 = skb[(size_t)clampi((K) + 5) * TLEN];                                  \
    c6 = skb[(size_t)clampi((K) + 6) * TLEN];                                  \
    c7 = skb[(size_t)clampi((K) + 7) * TLEN];

__global__ __launch_bounds__(512) void sdtw_dp(const float* __restrict__ skew,
                                               float* __restrict__ out) {
    const int b   = blockIdx.x;
    const int tid = threadIdx.x;
    const int ww  = tid >> 6;                    // hardware wave id
    const int c   = ((ww & 3) << 1) | (ww >> 2); // chunk (SIMD-aware remap)
    const int lt  = tid & 63;
    const int row = 64 * c + lt;
    const float* skb = skew + (size_t)b * (NDIAG * TLEN) + row;

    __shared__ float4 bnd4[9][8];                // [consumer chunk][quad slot]
    if (tid < 288) ((float*)bnd4)[tid] = BIGV;

    float P = BIGV, Q = BIGV;
    float vBig  = BIGV;
    float bd_up = BIGV;
    float dgs   = (tid == 0) ? 0.0f : BIGV;      // R(0,0)=0 at kd=0 (chunk0 lane0)
    float4 bq = make_float4(BIGV, BIGV, BIGV, BIGV);

    __syncthreads();

    float c0, c1, c2, c3, c4, c5, c6, c7;
    PRIME(-16 * c)                               // real for chunk 0; re-primed at warm-up

    for (int s = 0; s < 71; ++s) {
        const int sw  = s - 5 * c;               // wave-uniform
        const int kd0 = 16 * (s - c);
        const int q0  = (kd0 >> 2) & 7;
        const int vb0 = kd0 - row;

        if (sw >= -1 && sw <= 35) {
            float4 nq0 = bnd4[c][q0];
            float4 nq1 = bnd4[c][(q0 + 1) & 7];
            float4 nq2 = bnd4[c][(q0 + 2) & 7];
            float4 nq3 = bnd4[c][(q0 + 3) & 7];
            if (sw == -1) { PRIME(kd0) }         // warm-up: re-prime prefetch
            if (sw >= 4 && sw <= 31) { SEG_BODY(0, 0) }   // interior
            else                     { SEG_BODY(1, 1) }   // staircase/warm-up
        } else {
            if (lt == 63) {                      // junk: keep boundary cadence
                float4 bigq = make_float4(BIGV, BIGV, BIGV, BIGV);
                bnd4[c + 1][q0]           = bigq;
                bnd4[c + 1][(q0 + 1) & 7] = bigq;
                bnd4[c + 1][(q0 + 2) & 7] = bigq;
                bnd4[c + 1][(q0 + 3) & 7] = bigq;
            }
        }
        __syncthreads();
    }

    if (tid == 511) out[b] = Q * LN2;            // chunk 7, row 511: R'(512,512)*ln2
}

// ---------------------------------------------------------------- launcher
extern "C" void kernel_launch(void* const* d_in, const int* in_sizes, int n_in,
                              void* d_out, int out_size, void* d_ws, size_t ws_size,
                              hipStream_t stream) {
    const float* x = (const float*)d_in[0];
    const float* y = (const float*)d_in[1];
    float* outp = (float*)d_out;

    float* skew = (float*)d_ws;                  // 16,760,832 floats

    sdtw_gemm_skew<<<dim3(4, 4, BT), dim3(256), 0, stream>>>(x, y, skew);
    sdtw_dp<<<dim3(BT), dim3(512), 0, stream>>>(skew, outp);
}

// Round 15
// 139.339 us; speedup vs baseline: 1.6168x; 1.1104x over previous
//
#include <hip/hip_runtime.h>
#include <hip/hip_bf16.h>
#include <cstdint>

// Problem: B=32, T1=T2=512, D=128, gamma=1.0
// out[b] = softDTW( 1 - cos_sim(x[b], y[b]) )
//
// ws layout (floats):
//   skew : 32*1023*512 = 16,760,832   (cost/ln2 in anti-diagonal layout)

#define BT      32
#define TLEN    512
#define DF      128
#define NDIAG   1023          // kd = 0..1022  (kd = i-1 + j-1)
#define BIGV    1e30f
#define INV_LN2 1.44269504088896340f
#define LN2     0.69314718055994531f

// ------------------------------------------------- cosine-dist GEMM -> skew
// R15: 64x128 tile, grid (4,8,32) = 1024 blocks = 4 blocks/CU (was 2,
// grid-limited) -> 4 waves/SIMD hide K-loop ds_read latency. acc[4][8].
// Norms fused (sumsq during staging + aligned-8-lane shfl_xor reduce).
// LDS: stage xs[32][68]+ys[32][132] = 6400 f; epilogue cs[64][130] = 8320 f
// (reused); ~34 KB/block.
#define KC    32
#define SPADX 68
#define SPADY 132

__global__ __launch_bounds__(256) void sdtw_gemm_skew(const float* __restrict__ x,
                                                      const float* __restrict__ y,
                                                      float* __restrict__ skew) {
    __shared__ float smem[8320];             // max(stage 6400, epi 8320)
    __shared__ float rsx[64], rsy[128];      // row/col sumsq
    float* xs = smem;                        // [KC][SPADX]: xs[k][row], 64 rows
    float* ys = smem + KC * SPADX;           // [KC][SPADY]: ys[k][col], 128 cols

    const int b  = blockIdx.z;
    const int r0 = blockIdx.y * 64;
    const int c0 = blockIdx.x * 128;
    const int tid = threadIdx.x;
    const int tx = tid & 15, ty = tid >> 4;

    const float* xb = x + ((size_t)b * TLEN + r0) * DF;
    const float* yb = y + ((size_t)b * TLEN + c0) * DF;

    float acc[4][8];
    #pragma unroll
    for (int i = 0; i < 4; ++i)
        #pragma unroll
        for (int j = 0; j < 8; ++j) acc[i][j] = 0.0f;

    float psx[2] = {0, 0}, psy[4] = {0, 0, 0, 0};

    // register prefetch of chunk 0 (per-thread coords fixed across chunks)
    float4 rx[2], ry[4];
    #pragma unroll
    for (int i = 0; i < 2; ++i) {
        int g = tid + i * 256, row = g >> 3, kq = g & 7;
        rx[i] = *reinterpret_cast<const float4*>(xb + (size_t)row * DF + kq * 4);
    }
    #pragma unroll
    for (int i = 0; i < 4; ++i) {
        int g = tid + i * 256, row = g >> 3, kq = g & 7;
        ry[i] = *reinterpret_cast<const float4*>(yb + (size_t)row * DF + kq * 4);
    }

    for (int kb = 0; kb < DF; kb += KC) {
        __syncthreads();
        #pragma unroll
        for (int i = 0; i < 2; ++i) {
            int g = tid + i * 256, row = g >> 3, kq = g & 7;
            xs[(kq * 4 + 0) * SPADX + row] = rx[i].x;
            xs[(kq * 4 + 1) * SPADX + row] = rx[i].y;
            xs[(kq * 4 + 2) * SPADX + row] = rx[i].z;
            xs[(kq * 4 + 3) * SPADX + row] = rx[i].w;
            psx[i] = fmaf(rx[i].x, rx[i].x, psx[i]);
            psx[i] = fmaf(rx[i].y, rx[i].y, psx[i]);
            psx[i] = fmaf(rx[i].z, rx[i].z, psx[i]);
            psx[i] = fmaf(rx[i].w, rx[i].w, psx[i]);
        }
        #pragma unroll
        for (int i = 0; i < 4; ++i) {
            int g = tid + i * 256, row = g >> 3, kq = g & 7;
            ys[(kq * 4 + 0) * SPADY + row] = ry[i].x;
            ys[(kq * 4 + 1) * SPADY + row] = ry[i].y;
            ys[(kq * 4 + 2) * SPADY + row] = ry[i].z;
            ys[(kq * 4 + 3) * SPADY + row] = ry[i].w;
            psy[i] = fmaf(ry[i].x, ry[i].x, psy[i]);
            psy[i] = fmaf(ry[i].y, ry[i].y, psy[i]);
            psy[i] = fmaf(ry[i].z, ry[i].z, psy[i]);
            psy[i] = fmaf(ry[i].w, ry[i].w, psy[i]);
        }
        __syncthreads();
        if (kb + KC < DF) {
            #pragma unroll
            for (int i = 0; i < 2; ++i) {
                int g = tid + i * 256, row = g >> 3, kq = g & 7;
                rx[i] = *reinterpret_cast<const float4*>(xb + (size_t)row * DF + (kb + KC) + kq * 4);
            }
            #pragma unroll
            for (int i = 0; i < 4; ++i) {
                int g = tid + i * 256, row = g >> 3, kq = g & 7;
                ry[i] = *reinterpret_cast<const float4*>(yb + (size_t)row * DF + (kb + KC) + kq * 4);
            }
        }
        #pragma unroll
        for (int k = 0; k < KC; ++k) {
            float ax[4], ay[8];
            *reinterpret_cast<float4*>(&ax[0]) = *reinterpret_cast<const float4*>(&xs[k * SPADX + ty * 4]);
            *reinterpret_cast<float4*>(&ay[0]) = *reinterpret_cast<const float4*>(&ys[k * SPADY + tx * 8]);
            *reinterpret_cast<float4*>(&ay[4]) = *reinterpret_cast<const float4*>(&ys[k * SPADY + tx * 8 + 4]);
            #pragma unroll
            for (int i = 0; i < 4; ++i)
                #pragma unroll
                for (int j = 0; j < 8; ++j)
                    acc[i][j] = fmaf(ax[i], ay[j], acc[i][j]);
        }
    }

    // sumsq reduce within each aligned 8-lane group (kq = 0..7)
    #pragma unroll
    for (int o = 1; o <= 4; o <<= 1) {
        psx[0] += __shfl_xor(psx[0], o);
        psx[1] += __shfl_xor(psx[1], o);
        psy[0] += __shfl_xor(psy[0], o);
        psy[1] += __shfl_xor(psy[1], o);
        psy[2] += __shfl_xor(psy[2], o);
        psy[3] += __shfl_xor(psy[3], o);
    }
    if ((tid & 7) == 0) {
        #pragma unroll
        for (int i = 0; i < 2; ++i) rsx[(tid + i * 256) >> 3] = psx[i];
        #pragma unroll
        for (int i = 0; i < 4; ++i) rsy[(tid + i * 256) >> 3] = psy[i];
    }

    __syncthreads();
    float rn[4], cn[8];
    #pragma unroll
    for (int i = 0; i < 4; ++i) rn[i] = 1.0f / fmaxf(sqrtf(rsx[ty * 4 + i]), 1e-12f);
    #pragma unroll
    for (int j = 0; j < 8; ++j) cn[j] = 1.0f / fmaxf(sqrtf(rsy[tx * 8 + j]), 1e-12f);

    float* cs = smem;                        // [64][130], reuses staging space
    #pragma unroll
    for (int i = 0; i < 4; ++i)
        #pragma unroll
        for (int j = 0; j < 8; ++j)
            cs[(ty * 4 + i) * 130 + tx * 8 + j] =
                (1.0f - acc[i][j] * rn[i] * cn[j]) * INV_LN2;
    __syncthreads();

    // anti-diagonal scatter: skew[kd*512 + r], contiguous in r
    float* sk = skew + (size_t)b * (NDIAG * TLEN);
    const int wv = tid >> 6, l = tid & 63;
    for (int dd = wv; dd < 191; dd += 4) {
        int lo = max(0, dd - 127), hi = min(63, dd);
        int rl = lo + l;
        if (rl <= hi)
            sk[(size_t)(r0 + c0 + dd) * TLEN + r0 + rl] = cs[rl * 129 + dd];  // rl*130+(dd-rl)
    }
}

// ----------------------------------------------------------------- DTW DP
// (R9/R14 kernel, measured best ~91 us — unchanged.)
// 8 waves per batch (512 threads), lane owns row r = 64*chunk + lt; chunk
// remap c = ((ww&3)<<1)|(ww>>2). Chunk c processes diag kd at phase
// p = kd + 16c; one __syncthreads per 16-phase segment. Modes: JUNK /
// PARTIAL(mask+clamp; sw==-1 warm-up re-primes prefetch) / INTERIOR.
// Lane-0 patch via DPP wave_shr:1 old=bd_up; dg carried in dgs. Boundary
// quads hoisted at segment start. 71*16 = 1136 phases; answer: diag 1022
// (even -> Q) of chunk 7 lane 63 = tid 511.

__device__ __forceinline__ int clampi(int v) {
    return v < 0 ? 0 : (v > NDIAG - 1 ? NDIAG - 1 : v);
}

__device__ __forceinline__ float dpp_shr1_old(float old, float x) {
    return __builtin_bit_cast(float,
        __builtin_amdgcn_update_dpp(__builtin_bit_cast(int, old),
                                    __builtin_bit_cast(int, x),
                                    0x138 /*wave_shr:1*/, 0xF, 0xF, false));
}

#define PH(s, CC, PN, PO, NQC, MASKED, CLAMPED)                                \
  {                                                                            \
    float up_ = dpp_shr1_old(bd_up, PN);     /* lane0 <- bd_up */              \
    float dg_ = dgs;                         /* patched up_ of prev phase */   \
    float m_   = fminf(fminf(dg_, PN), up_);                                   \
    float mid_ = __builtin_amdgcn_fmed3f(dg_, PN, up_);                        \
    float mx_  = fmaxf(fmaxf(dg_, PN), up_);                                   \
    float e_   = 1.0f + __builtin_amdgcn_exp2f(m_ - mid_)                      \
                      + __builtin_amdgcn_exp2f(m_ - mx_);                      \
    float v_   = CC + m_ - __builtin_amdgcn_logf(e_);                          \
    PO = (MASKED) ? (((unsigned)(vb0 + (s)) < 512u) ? v_ : vBig) : v_;         \
    if (((s) & 3) == 0) bq.x = PO;                                             \
    if (((s) & 3) == 1) bq.y = PO;                                             \
    if (((s) & 3) == 2) bq.z = PO;                                             \
    if (((s) & 3) == 3) { bq.w = PO;                                           \
      if (lt == 63) bnd4[c + 1][(q0 + ((s) >> 2)) & 7] = bq; }                 \
    bd_up = (NQC);                                                             \
    dgs = up_;                                                                 \
    { int kl_ = kd0 + (s) + 8; if (CLAMPED) kl_ = clampi(kl_);                 \
      CC = skb[(size_t)kl_ * TLEN]; }                                          \
  }

#define SEG_BODY(MASKED, CLAMPED)                                              \
    PH(0,  c0, P, Q, nq0.x, MASKED, CLAMPED) PH(1,  c1, Q, P, nq0.y, MASKED, CLAMPED) \
    PH(2,  c2, P, Q, nq0.z, MASKED, CLAMPED) PH(3,  c3, Q, P, nq0.w, MASKED, CLAMPED) \
    PH(4,  c4, P, Q, nq1.x, MASKED, CLAMPED) PH(5,  c5, Q, P, nq1.y, MASKED, CLAMPED) \
    PH(6,  c6, P, Q, nq1.z, MASKED, CLAMPED) PH(7,  c7, Q, P, nq1.w, MASKED, CLAMPED) \
    PH(8,  c0, P, Q, nq2.x, MASKED, CLAMPED) PH(9,  c1, Q, P, nq2.y, MASKED, CLAMPED) \
    PH(10, c2, P, Q, nq2.z, MASKED, CLAMPED) PH(11, c3, Q, P, nq2.w, MASKED, CLAMPED) \
    PH(12, c4, P, Q, nq3.x, MASKED, CLAMPED) PH(13, c5, Q, P, nq3.y, MASKED, CLAMPED) \
    PH(14, c6, P, Q, nq3.z, MASKED, CLAMPED) PH(15, c7, Q, P, nq3.w, MASKED, CLAMPED)

#define PRIME(K)                                                               \
    c0 = skb[(size_t)clampi((K) + 0) * TLEN];                                  \
    c1 = skb[(size_t)clampi((K) + 1) * TLEN];                                  \
    c2 = skb[(size_t)clampi((K) + 2) * TLEN];                                  \
    c3 = skb[(size_t)clampi((K) + 3) * TLEN];                                  \
    c4 = skb[(size_t)clampi((K) + 4) * TLEN];                                  \
    c5 = skb[(size_t)clampi((K) + 5) * TLEN];                                  \
    c6 = skb[(size_t)clampi((K) + 6) * TLEN];                                  \
    c7 = skb[(size_t)clampi((K) + 7) * TLEN];

__global__ __launch_bounds__(512) void sdtw_dp(const float* __restrict__ skew,
                                               float* __restrict__ out) {
    const int b   = blockIdx.x;
    const int tid = threadIdx.x;
    const int ww  = tid >> 6;                    // hardware wave id
    const int c   = ((ww & 3) << 1) | (ww >> 2); // chunk (SIMD-aware remap)
    const int lt  = tid & 63;
    const int row = 64 * c + lt;
    const float* skb = skew + (size_t)b * (NDIAG * TLEN) + row;

    __shared__ float4 bnd4[9][8];                // [consumer chunk][quad slot]
    if (tid < 288) ((float*)bnd4)[tid] = BIGV;

    float P = BIGV, Q = BIGV;
    float vBig  = BIGV;
    float bd_up = BIGV;
    float dgs   = (tid == 0) ? 0.0f : BIGV;      // R(0,0)=0 at kd=0 (chunk0 lane0)
    float4 bq = make_float4(BIGV, BIGV, BIGV, BIGV);

    __syncthreads();

    float c0, c1, c2, c3, c4, c5, c6, c7;
    PRIME(-16 * c)                               // real for chunk 0; re-primed at warm-up

    for (int s = 0; s < 71; ++s) {
        const int sw  = s - 5 * c;               // wave-uniform
        const int kd0 = 16 * (s - c);
        const int q0  = (kd0 >> 2) & 7;
        const int vb0 = kd0 - row;

        if (sw >= -1 && sw <= 35) {
            float4 nq0 = bnd4[c][q0];
            float4 nq1 = bnd4[c][(q0 + 1) & 7];
            float4 nq2 = bnd4[c][(q0 + 2) & 7];
            float4 nq3 = bnd4[c][(q0 + 3) & 7];
            if (sw == -1) { PRIME(kd0) }         // warm-up: re-prime prefetch
            if (sw >= 4 && sw <= 31) { SEG_BODY(0, 0) }   // interior
            else                     { SEG_BODY(1, 1) }   // staircase/warm-up
        } else {
            if (lt == 63) {                      // junk: keep boundary cadence
                float4 bigq = make_float4(BIGV, BIGV, BIGV, BIGV);
                bnd4[c + 1][q0]           = bigq;
                bnd4[c + 1][(q0 + 1) & 7] = bigq;
                bnd4[c + 1][(q0 + 2) & 7] = bigq;
                bnd4[c + 1][(q0 + 3) & 7] = bigq;
            }
        }
        __syncthreads();
    }

    if (tid == 511) out[b] = Q * LN2;            // chunk 7, row 511: R'(512,512)*ln2
}

// ---------------------------------------------------------------- launcher
extern "C" void kernel_launch(void* const* d_in, const int* in_sizes, int n_in,
                              void* d_out, int out_size, void* d_ws, size_t ws_size,
                              hipStream_t stream) {
    const float* x = (const float*)d_in[0];
    const float* y = (const float*)d_in[1];
    float* outp = (float*)d_out;

    float* skew = (float*)d_ws;                  // 16,760,832 floats

    sdtw_gemm_skew<<<dim3(4, 8, BT), dim3(256), 0, stream>>>(x, y, skew);
    sdtw_dp<<<dim3(BT), dim3(512), 0, stream>>>(skew, outp);
}